// Round 3
// baseline (1623.149 us; speedup 1.0000x reference)
//
#include <hip/hip_runtime.h>
#include <hip/hip_bf16.h>

#define NNODES 20000
#define NEDGES 320000
#define NGRAPH 1000

typedef __hip_bfloat16 bf16;

__device__ __forceinline__ float b2f(bf16 x) { return __bfloat162float(x); }

// monotonic float->uint encoding for atomic max (0 sorts below any real value)
__device__ __forceinline__ unsigned fenc(float x) {
    unsigned u = __float_as_uint(x);
    return (u & 0x80000000u) ? ~u : (u | 0x80000000u);
}
__device__ __forceinline__ float fdec(unsigned u) {
    return (u & 0x80000000u) ? __uint_as_float(u & 0x7fffffffu) : __uint_as_float(~u);
}

// width-agnostic index fetch (int32 or int64 storage)
__device__ __forceinline__ int idx_at(const void* p, int i, int is64) {
    return is64 ? (int)((const long long*)p)[i] : ((const int*)p)[i];
}

// ---------------------------------------------------------------------------
// sniff input encodings:
//  flags[0]: float tensors are bf16 (1) or fp32 (0)
//  flags[1]: edge_index is int64 (1) or int32 (0)
//  flags[2]: batch      is int64 (1) or int32 (0)
// bf16 test: fp32-truth makes ~45% of bf16-decodes implausible; bf16-truth ties.
// int64 test: high words (odd int32 slots) are all zero for small positive ints.
// ---------------------------------------------------------------------------
__global__ void sniff_all(const void* __restrict__ x, const void* __restrict__ ei,
                          const void* __restrict__ batch, int* __restrict__ flags) {
    __shared__ int sb[4];  // good_bf, good_f32, zeros_ei_odd, zeros_batch_odd
    if (threadIdx.x < 4) sb[threadIdx.x] = 0;
    __syncthreads();
    int gb = 0, gf = 0, ze = 0, zb = 0;
    for (int i = threadIdx.x; i < 8192; i += blockDim.x) {
        float vb = b2f(((const bf16*)x)[i]);
        float vf = ((const float*)x)[i];
        if (fabsf(vb) < 1e4f) gb++;   // NaN fails -> counted bad
        if (fabsf(vf) < 1e4f) gf++;
        if (((const int*)ei)[2 * i + 1] == 0) ze++;
        if (((const int*)batch)[2 * i + 1] == 0) zb++;
    }
    atomicAdd(&sb[0], gb);
    atomicAdd(&sb[1], gf);
    atomicAdd(&sb[2], ze);
    atomicAdd(&sb[3], zb);
    __syncthreads();
    if (threadIdx.x == 0) {
        flags[0] = (sb[0] >= sb[1]) ? 1 : 0;
        flags[1] = (sb[2] > 6000) ? 1 : 0;  // ~8192 zeros if int64, ~0 if int32
        flags[2] = (sb[3] > 6000) ? 1 : 0;
    }
}

// ---------------------------------------------------------------------------
// canonicalize all float inputs into fp32 scratch
// ---------------------------------------------------------------------------
struct Segs {
    const void* src[29];
    int off[30];
};

__global__ void convert_inputs(Segs S, const int* __restrict__ flags,
                               float* __restrict__ dst, int total) {
    int i = blockIdx.x * blockDim.x + threadIdx.x;
    if (i >= total) return;
    bool isbf = flags[0] != 0;
    int s = 0;
    while (i >= S.off[s + 1]) s++;
    int j = i - S.off[s];
    dst[i] = isbf ? b2f(((const bf16*)S.src[s])[j]) : ((const float*)S.src[s])[j];
}

// ---------------------------------------------------------------------------
// Fused lin_l / lin_r: XL = X@Wl + bl, XR = X@Wr + br  (all fp32)
// block = Dout threads, R rows per block, X rows staged transposed in LDS
// ---------------------------------------------------------------------------
template <int R>
__global__ void lin_lr(const float* __restrict__ X, int Cin, int Dout,
                       const float* __restrict__ Wl, const float* __restrict__ bl,
                       const float* __restrict__ Wr, const float* __restrict__ br,
                       float* __restrict__ XL, float* __restrict__ XR) {
    extern __shared__ float xs[];  // [Cin][R]
    const int c = threadIdx.x;
    const int r0 = blockIdx.x * R;

    for (int i = c; i < R * Cin; i += blockDim.x) {
        int r = i / Cin, k = i - r * Cin;
        int row = r0 + r;
        xs[k * R + r] = (row < NNODES) ? X[row * Cin + k] : 0.f;
    }
    __syncthreads();

    float accL[R], accR[R];
#pragma unroll
    for (int r = 0; r < R; r++) { accL[r] = 0.f; accR[r] = 0.f; }

    for (int k = 0; k < Cin; k++) {
        float wl = Wl[k * Dout + c];
        float wr = Wr[k * Dout + c];
#pragma unroll
        for (int r = 0; r < R; r++) {
            float xv = xs[k * R + r];
            accL[r] = fmaf(xv, wl, accL[r]);
            accR[r] = fmaf(xv, wr, accR[r]);
        }
    }
    float bL = bl[c], bR = br[c];
#pragma unroll
    for (int r = 0; r < R; r++) {
        int row = r0 + r;
        if (row < NNODES) {
            XL[row * Dout + c] = accL[r] + bL;
            XR[row * Dout + c] = accR[r] + bR;
        }
    }
}

// ---------------------------------------------------------------------------
// per-(edge,head) wave: logit = sum_c leakyrelu(xl[src]+xr[dst]+ee, .2)*att
// then atomic segment-max over dst
// ---------------------------------------------------------------------------
template <int H, int HSHIFT>
__global__ void edge_logits(const float* __restrict__ XL, const float* __restrict__ XR,
                            const void* __restrict__ ei, const int* __restrict__ flags,
                            const float* __restrict__ ea,
                            const float* __restrict__ We, const float* __restrict__ att,
                            float* __restrict__ logit, unsigned* __restrict__ maxe) {
    const int Dout = H * 64;
    int gid = blockIdx.x * blockDim.x + threadIdx.x;
    int w = gid >> 6, lane = gid & 63;
    if (w >= NEDGES * H) return;
    const int i64 = flags[1];
    int e = w >> HSHIFT, h = w & (H - 1);
    int src = idx_at(ei, e, i64), dst = idx_at(ei, NEDGES + e, i64);
    int j = (h << 6) + lane;

    float ee = 0.f;
#pragma unroll
    for (int k = 0; k < 4; k++)
        ee = fmaf(ea[e * 4 + k], We[k * Dout + j], ee);

    float z = XL[src * Dout + j] + XR[dst * Dout + j] + ee;
    z = z > 0.f ? z : 0.2f * z;
    float v = z * att[j];
#pragma unroll
    for (int o = 32; o; o >>= 1) v += __shfl_xor(v, o);
    if (lane == 0) {
        logit[w] = v;  // w == e*H + h
        atomicMax(&maxe[dst * H + h], fenc(v));
    }
}

// ---------------------------------------------------------------------------
// ex = exp(min(logit - m[dst], 0)); denom[dst] += ex   (in-place on logit buf)
// ---------------------------------------------------------------------------
template <int H, int HSHIFT>
__global__ void exp_denom(const void* __restrict__ ei, const int* __restrict__ flags,
                          float* __restrict__ exlog,
                          const unsigned* __restrict__ maxe, float* __restrict__ den) {
    int i = blockIdx.x * blockDim.x + threadIdx.x;
    if (i >= NEDGES * H) return;
    int e = i >> HSHIFT, h = i & (H - 1);
    int dst = idx_at(ei, NEDGES + e, flags[1]);
    float m = fdec(maxe[dst * H + h]);
    float ex = expf(fminf(exlog[i] - m, 0.f));  // identity when max correct
    exlog[i] = ex;
    atomicAdd(&den[dst * H + h], ex);
}

// ---------------------------------------------------------------------------
// acc[dst,c] += (ex[e,h]/den[dst,h]) * XL[src,c]
// ---------------------------------------------------------------------------
template <int H, int DSHIFT>
__global__ void msg_scatter(const void* __restrict__ ei, const int* __restrict__ flags,
                            const float* __restrict__ exv,
                            const float* __restrict__ den, const float* __restrict__ XL,
                            float* __restrict__ acc) {
    const int Dout = 1 << DSHIFT;
    int i = blockIdx.x * blockDim.x + threadIdx.x;
    if (i >= NEDGES * Dout) return;
    const int i64 = flags[1];
    int e = i >> DSHIFT;
    int c = i & (Dout - 1);
    int h = c >> 6;
    int src = idx_at(ei, e, i64), dst = idx_at(ei, NEDGES + e, i64);
    float alpha = exv[e * H + h] / (den[dst * H + h] + 1e-16f);
    atomicAdd(&acc[dst * Dout + c], alpha * XL[src * Dout + c]);
}

// ---------------------------------------------------------------------------
// in-place epilogue: acc = act(acc + bias)
// ---------------------------------------------------------------------------
template <bool ELU>
__global__ void bias_act(float* __restrict__ acc, const float* __restrict__ bias, int Dout) {
    int i = blockIdx.x * blockDim.x + threadIdx.x;
    if (i >= NNODES * Dout) return;
    int c = i & (Dout - 1);
    float v = acc[i] + bias[c];
    if (ELU) v = v > 0.f ? v : expf(v) - 1.f;
    acc[i] = v;
}

// ---------------------------------------------------------------------------
// mean pool (atomic) over batch
// ---------------------------------------------------------------------------
__global__ void pool_kernel(const float* __restrict__ h, const void* __restrict__ batch,
                            const int* __restrict__ flags,
                            float* __restrict__ pool, float* __restrict__ cnt) {
    int i = blockIdx.x * blockDim.x + threadIdx.x;
    if (i >= NNODES * 64) return;
    int n = i >> 6, c = i & 63;
    int b = idx_at(batch, n, flags[2]);
    atomicAdd(&pool[b * 64 + c], h[i]);
    if (c == 0) atomicAdd(&cnt[b], 1.f);
}

// ---------------------------------------------------------------------------
// MLP head: one block (64 threads) per graph; fp32 output
// ---------------------------------------------------------------------------
__global__ void mlp_head(const float* __restrict__ pool, const float* __restrict__ cnt,
                         const float* __restrict__ mW1, const float* __restrict__ mb1,
                         const float* __restrict__ mW2, const float* __restrict__ mb2,
                         const float* __restrict__ mW3, const float* __restrict__ mb3,
                         float* __restrict__ out) {
    __shared__ float g[64], s1[32], s2[16];
    int b = blockIdx.x, t = threadIdx.x;
    float c = fmaxf(cnt[b], 1.f);
    g[t] = pool[b * 64 + t] / c;
    __syncthreads();
    if (t < 32) {
        float a = 0.f;
        for (int k = 0; k < 64; k++) a = fmaf(g[k], mW1[k * 32 + t], a);
        s1[t] = fmaxf(a + mb1[t], 0.f);
    }
    __syncthreads();
    if (t < 16) {
        float a = 0.f;
        for (int k = 0; k < 32; k++) a = fmaf(s1[k], mW2[k * 16 + t], a);
        s2[t] = fmaxf(a + mb2[t], 0.f);
    }
    __syncthreads();
    if (t < 4) {
        float a = 0.f;
        for (int k = 0; k < 16; k++) a = fmaf(s2[k], mW3[k * 4 + t], a);
        out[b * 4 + t] = a + mb3[t];
    }
}

// ---------------------------------------------------------------------------

extern "C" void kernel_launch(void* const* d_in, const int* in_sizes, int n_in,
                              void* d_out, int out_size, void* d_ws, size_t ws_size,
                              hipStream_t stream) {
    const void* ei    = d_in[1];
    const void* batch = d_in[3];

    // ---- canonicalization table: the 29 float inputs in dict order ----
    int fidx[29];
    fidx[0] = 0;  // x
    fidx[1] = 2;  // edge_attr
    for (int i = 0; i < 21; i++) fidx[2 + i] = 4 + i;
    for (int i = 0; i < 6; i++) fidx[23 + i] = 25 + i;

    Segs S;
    int off = 0;
    for (int i = 0; i < 29; i++) {
        S.src[i] = d_in[fidx[i]];
        S.off[i] = off;
        off += in_sizes[fidx[i]];
    }
    S.off[29] = off;
    const int total = off;  // ~1.70M floats

    // ---- workspace layout ----
    int*      FLAGS = (int*)d_ws;                    // 4 ints
    float*    CONV  = (float*)d_ws + 4;
    unsigned* MAXE  = (unsigned*)(CONV + total);     // N*4
    float*    DEN   = (float*)(MAXE + NNODES * 4);   // N*4
    float*    POOL  = DEN + NNODES * 4;              // G*64
    float*    CNT   = POOL + NGRAPH * 64;            // G
    float*    EXb   = CNT + NGRAPH;                  // E*4
    float*    XLb   = EXb + NEDGES * 4;              // N*256
    float*    XRb   = XLb + NNODES * 256;            // N*256
    float*    ACC   = XRb + NNODES * 256;            // N*256 (layer io, in-place)

    const float* CX  = CONV + S.off[0];
    const float* CEA = CONV + S.off[1];
    const float* CP[21];
    for (int i = 0; i < 21; i++) CP[i] = CONV + S.off[2 + i];
    const float* CmW1 = CONV + S.off[23];
    const float* Cmb1 = CONV + S.off[24];
    const float* CmW2 = CONV + S.off[25];
    const float* Cmb2 = CONV + S.off[26];
    const float* CmW3 = CONV + S.off[27];
    const float* Cmb3 = CONV + S.off[28];

    // ---- sniff encodings + canonicalize floats ----
    sniff_all<<<1, 256, 0, stream>>>(d_in[0], ei, batch, FLAGS);
    convert_inputs<<<(total + 255) / 256, 256, 0, stream>>>(S, FLAGS, CONV, total);

    constexpr int R = 8;
    const int linGrid = (NNODES + R - 1) / R;

    auto run_layer = [&](const float* Xin, int Cin, int H,
                         const float* Wl, const float* bl, const float* Wr, const float* br,
                         const float* We, const float* att, const float* bias, bool elu) {
        const int Dout = H * 64;

        size_t shmem = (size_t)R * Cin * sizeof(float);
        lin_lr<R><<<linGrid, Dout, shmem, stream>>>(Xin, Cin, Dout, Wl, bl, Wr, br, XLb, XRb);

        // Xin (== ACC for layers 2/3) is dead now; zero the accumulators
        hipMemsetAsync(ACC, 0, sizeof(float) * NNODES * Dout, stream);
        hipMemsetAsync(MAXE, 0, sizeof(unsigned) * NNODES * H, stream);
        hipMemsetAsync(DEN, 0, sizeof(float) * NNODES * H, stream);

        int waves = NEDGES * H;
        int thr = waves * 64;
        if (H == 4) {
            edge_logits<4, 2><<<(thr + 255) / 256, 256, 0, stream>>>(XLb, XRb, ei, FLAGS, CEA, We, att, EXb, MAXE);
            exp_denom<4, 2><<<(waves + 255) / 256, 256, 0, stream>>>(ei, FLAGS, EXb, MAXE, DEN);
            int tot = NEDGES * 256;
            msg_scatter<4, 8><<<(tot + 255) / 256, 256, 0, stream>>>(ei, FLAGS, EXb, DEN, XLb, ACC);
        } else {
            edge_logits<1, 0><<<(thr + 255) / 256, 256, 0, stream>>>(XLb, XRb, ei, FLAGS, CEA, We, att, EXb, MAXE);
            exp_denom<1, 0><<<(waves + 255) / 256, 256, 0, stream>>>(ei, FLAGS, EXb, MAXE, DEN);
            int tot = NEDGES * 64;
            msg_scatter<1, 6><<<(tot + 255) / 256, 256, 0, stream>>>(ei, FLAGS, EXb, DEN, XLb, ACC);
        }
        int n2 = NNODES * Dout;
        if (elu)
            bias_act<true><<<(n2 + 255) / 256, 256, 0, stream>>>(ACC, bias, Dout);
        else
            bias_act<false><<<(n2 + 255) / 256, 256, 0, stream>>>(ACC, bias, Dout);
    };

    // layer 1: CX (N x 12) -> ACC (N x 256), ELU
    run_layer(CX, 12, 4, CP[0], CP[1], CP[2], CP[3], CP[4], CP[5], CP[6], true);
    // layer 2: ACC (N x 256) -> ACC, ELU
    run_layer(ACC, 256, 4, CP[7], CP[8], CP[9], CP[10], CP[11], CP[12], CP[13], true);
    // layer 3: ACC (N x 256) -> ACC (N x 64), no act
    run_layer(ACC, 256, 1, CP[14], CP[15], CP[16], CP[17], CP[18], CP[19], CP[20], false);

    // global mean pool + MLP head
    hipMemsetAsync(POOL, 0, sizeof(float) * (NGRAPH * 64 + NGRAPH), stream);
    pool_kernel<<<(NNODES * 64 + 255) / 256, 256, 0, stream>>>(ACC, batch, FLAGS, POOL, CNT);
    mlp_head<<<NGRAPH, 64, 0, stream>>>(POOL, CNT, CmW1, Cmb1, CmW2, Cmb2, CmW3, Cmb3, (float*)d_out);
}

// Round 4
// 673.527 us; speedup vs baseline: 2.4099x; 2.4099x over previous
//
#include <hip/hip_runtime.h>
#include <hip/hip_bf16.h>

#define NNODES 20000
#define NEDGES 320000
#define NGRAPH 1000

typedef __hip_bfloat16 bf16;

__device__ __forceinline__ float b2f(bf16 x) { return __bfloat162float(x); }

// width-agnostic index fetch (int32 or int64 storage)
__device__ __forceinline__ int idx_at(const void* p, int i, int is64) {
    return is64 ? (int)((const long long*)p)[i] : ((const int*)p)[i];
}

// ---------------------------------------------------------------------------
// sniff input encodings (flags[0]: floats bf16?, flags[1]: ei int64?, flags[2]: batch int64?)
// ---------------------------------------------------------------------------
__global__ void sniff_all(const void* __restrict__ x, const void* __restrict__ ei,
                          const void* __restrict__ batch, int* __restrict__ flags) {
    __shared__ int sb[4];
    if (threadIdx.x < 4) sb[threadIdx.x] = 0;
    __syncthreads();
    int gb = 0, gf = 0, ze = 0, zb = 0;
    for (int i = threadIdx.x; i < 8192; i += blockDim.x) {
        float vb = b2f(((const bf16*)x)[i]);
        float vf = ((const float*)x)[i];
        if (fabsf(vb) < 1e4f) gb++;
        if (fabsf(vf) < 1e4f) gf++;
        if (((const int*)ei)[2 * i + 1] == 0) ze++;
        if (((const int*)batch)[2 * i + 1] == 0) zb++;
    }
    atomicAdd(&sb[0], gb); atomicAdd(&sb[1], gf);
    atomicAdd(&sb[2], ze); atomicAdd(&sb[3], zb);
    __syncthreads();
    if (threadIdx.x == 0) {
        flags[0] = (sb[0] >= sb[1]) ? 1 : 0;
        flags[1] = (sb[2] > 6000) ? 1 : 0;
        flags[2] = (sb[3] > 6000) ? 1 : 0;
    }
}

// ---------------------------------------------------------------------------
// canonicalize all float inputs into fp32 scratch
// ---------------------------------------------------------------------------
struct Segs {
    const void* src[29];
    int off[30];
};

__global__ void convert_inputs(Segs S, const int* __restrict__ flags,
                               float* __restrict__ dst, int total) {
    int i = blockIdx.x * blockDim.x + threadIdx.x;
    if (i >= total) return;
    bool isbf = flags[0] != 0;
    int s = 0;
    while (i >= S.off[s + 1]) s++;
    int j = i - S.off[s];
    dst[i] = isbf ? b2f(((const bf16*)S.src[s])[j]) : ((const float*)S.src[s])[j];
}

// ---------------------------------------------------------------------------
// CSR build: histogram -> single-block scan -> scatter (dst-sorted edge list)
// ---------------------------------------------------------------------------
__global__ void csr_hist(const void* __restrict__ ei, const int* __restrict__ flags,
                         int* __restrict__ deg) {
    int e = blockIdx.x * blockDim.x + threadIdx.x;
    if (e >= NEDGES) return;
    atomicAdd(&deg[idx_at(ei, NEDGES + e, flags[1])], 1);
}

__global__ void csr_scan(const int* __restrict__ deg, int* __restrict__ rowptr,
                         int* __restrict__ cursor) {
    __shared__ int buf[1024];
    __shared__ int carry;
    int t = threadIdx.x;
    if (t == 0) carry = 0;
    __syncthreads();
    for (int base = 0; base < NNODES; base += 1024) {
        int i = base + t;
        int v = (i < NNODES) ? deg[i] : 0;
        buf[t] = v;
        __syncthreads();
        for (int o = 1; o < 1024; o <<= 1) {
            int add = (t >= o) ? buf[t - o] : 0;
            __syncthreads();
            buf[t] += add;
            __syncthreads();
        }
        int incl = buf[t];
        int excl = incl - v;
        int c0 = carry;  // stable: last write was before a barrier
        if (i < NNODES) { rowptr[i] = c0 + excl; cursor[i] = c0 + excl; }
        __syncthreads();
        if (t == 1023) carry = c0 + incl;
        __syncthreads();
    }
    if (t == 0) rowptr[NNODES] = carry;
}

__global__ void csr_scatter(const void* __restrict__ ei, const int* __restrict__ flags,
                            int* __restrict__ cursor, int2* __restrict__ csr) {
    int e = blockIdx.x * blockDim.x + threadIdx.x;
    if (e >= NEDGES) return;
    const int i64 = flags[1];
    int src = idx_at(ei, e, i64), dst = idx_at(ei, NEDGES + e, i64);
    int pos = atomicAdd(&cursor[dst], 1);
    csr[pos] = make_int2(src, e);
}

// ---------------------------------------------------------------------------
// Fused lin_l / lin_r: XL = X@Wl + bl, XR = X@Wr + br
// block = Dout threads, R rows per block, X rows staged transposed in LDS
// ---------------------------------------------------------------------------
template <int R, int CIN>
__global__ void lin_lr(const float* __restrict__ X, int Dout,
                       const float* __restrict__ Wl, const float* __restrict__ bl,
                       const float* __restrict__ Wr, const float* __restrict__ br,
                       float* __restrict__ XL, float* __restrict__ XR) {
    __shared__ float xs[CIN * R];
    const int c = threadIdx.x;
    const int r0 = blockIdx.x * R;

    for (int i = c; i < R * CIN; i += blockDim.x) {
        int r = i / CIN, k = i - r * CIN;
        int row = r0 + r;
        xs[k * R + r] = (row < NNODES) ? X[row * CIN + k] : 0.f;
    }
    __syncthreads();

    float accL[R], accR[R];
#pragma unroll
    for (int r = 0; r < R; r++) { accL[r] = 0.f; accR[r] = 0.f; }

    for (int k = 0; k < CIN; k++) {
        float wl = Wl[k * Dout + c];
        float wr = Wr[k * Dout + c];
#pragma unroll
        for (int r = 0; r < R; r++) {
            float xv = xs[k * R + r];
            accL[r] = fmaf(xv, wl, accL[r]);
            accR[r] = fmaf(xv, wr, accR[r]);
        }
    }
    float bL = bl[c], bR = br[c];
#pragma unroll
    for (int r = 0; r < R; r++) {
        int row = r0 + r;
        if (row < NNODES) {
            XL[row * Dout + c] = accL[r] + bL;
            XR[row * Dout + c] = accR[r] + bR;
        }
    }
}

// ---------------------------------------------------------------------------
// Fused GATv2 edge pipeline, one block per dst node, one wave per head.
// Online softmax over the dst's CSR edge list; no atomics, no score buffers.
//   logit_e = sum_c leakyrelu(XL[src,c]+XR[dst,c]+ (ea[e]@We)_c, .2) * att_c
//   out[dst,c] = sum_e softmax_e(logit) * XL[src,c]  (+bias, opt ELU)
// ---------------------------------------------------------------------------
template <int H, bool ELU>
__global__ void gat_agg(const int* __restrict__ rowptr, const int2* __restrict__ csr,
                        const float* __restrict__ XL, const float* __restrict__ XR,
                        const float* __restrict__ ea,   // [E][4] fp32, 16B aligned
                        const float* __restrict__ We, const float* __restrict__ att,
                        const float* __restrict__ bias, float* __restrict__ out) {
    const int Dout = H * 64;
    const int dst = blockIdx.x;
    const int t = threadIdx.x;  // channel c = h*64 + lane; wave == head

    float xr = XR[dst * Dout + t];
    float w0 = We[0 * Dout + t], w1 = We[1 * Dout + t];
    float w2 = We[2 * Dout + t], w3 = We[3 * Dout + t];
    float av = att[t];

    int i0 = rowptr[dst], i1 = rowptr[dst + 1];
    float m = -INFINITY, l = 0.f, acc = 0.f;

    for (int i = i0; i < i1; i++) {
        int2 se = csr[i];
        float4 e4 = ((const float4*)ea)[se.y];
        float xl = XL[se.x * Dout + t];
        float z = fmaf(e4.x, w0, fmaf(e4.y, w1, fmaf(e4.z, w2, fmaf(e4.w, w3, xl + xr))));
        z = z > 0.f ? z : 0.2f * z;
        float v = z * av;
#pragma unroll
        for (int o = 32; o; o >>= 1) v += __shfl_xor(v, o);
        // v is wave-uniform now: uniform branch, no divergence
        if (v <= m) {
            float p = expf(v - m);
            l += p;
            acc = fmaf(p, xl, acc);
        } else {
            float sc = expf(m - v);  // 0 on first edge (m = -inf)
            l = fmaf(l, sc, 1.f);
            acc = fmaf(acc, sc, xl);
            m = v;
        }
    }
    float o = acc / (l + 1e-16f) + bias[t];
    if (ELU) o = o > 0.f ? o : expf(o) - 1.f;
    out[dst * Dout + t] = o;
}

// ---------------------------------------------------------------------------
// mean pool (atomic) over batch
// ---------------------------------------------------------------------------
__global__ void pool_kernel(const float* __restrict__ h, const void* __restrict__ batch,
                            const int* __restrict__ flags,
                            float* __restrict__ pool, float* __restrict__ cnt) {
    int i = blockIdx.x * blockDim.x + threadIdx.x;
    if (i >= NNODES * 64) return;
    int n = i >> 6, c = i & 63;
    int b = idx_at(batch, n, flags[2]);
    atomicAdd(&pool[b * 64 + c], h[i]);
    if (c == 0) atomicAdd(&cnt[b], 1.f);
}

// ---------------------------------------------------------------------------
// MLP head: one block (64 threads) per graph; fp32 output
// ---------------------------------------------------------------------------
__global__ void mlp_head(const float* __restrict__ pool, const float* __restrict__ cnt,
                         const float* __restrict__ mW1, const float* __restrict__ mb1,
                         const float* __restrict__ mW2, const float* __restrict__ mb2,
                         const float* __restrict__ mW3, const float* __restrict__ mb3,
                         float* __restrict__ out) {
    __shared__ float g[64], s1[32], s2[16];
    int b = blockIdx.x, t = threadIdx.x;
    float c = fmaxf(cnt[b], 1.f);
    g[t] = pool[b * 64 + t] / c;
    __syncthreads();
    if (t < 32) {
        float a = 0.f;
        for (int k = 0; k < 64; k++) a = fmaf(g[k], mW1[k * 32 + t], a);
        s1[t] = fmaxf(a + mb1[t], 0.f);
    }
    __syncthreads();
    if (t < 16) {
        float a = 0.f;
        for (int k = 0; k < 32; k++) a = fmaf(s1[k], mW2[k * 16 + t], a);
        s2[t] = fmaxf(a + mb2[t], 0.f);
    }
    __syncthreads();
    if (t < 4) {
        float a = 0.f;
        for (int k = 0; k < 16; k++) a = fmaf(s2[k], mW3[k * 4 + t], a);
        out[b * 4 + t] = a + mb3[t];
    }
}

// ---------------------------------------------------------------------------

extern "C" void kernel_launch(void* const* d_in, const int* in_sizes, int n_in,
                              void* d_out, int out_size, void* d_ws, size_t ws_size,
                              hipStream_t stream) {
    const void* ei    = d_in[1];
    const void* batch = d_in[3];

    // ---- canonicalization table: the 29 float inputs in dict order ----
    int fidx[29];
    fidx[0] = 0;  // x
    fidx[1] = 2;  // edge_attr
    for (int i = 0; i < 21; i++) fidx[2 + i] = 4 + i;
    for (int i = 0; i < 6; i++) fidx[23 + i] = 25 + i;

    Segs S;
    int off = 0;
    for (int i = 0; i < 29; i++) {
        S.src[i] = d_in[fidx[i]];
        S.off[i] = off;
        off += in_sizes[fidx[i]];
    }
    S.off[29] = off;
    const int total = off;

    // ---- workspace layout ----
    int*      FLAGS  = (int*)d_ws;                    // 4 ints (16 B, keeps alignment)
    float*    CONV   = (float*)d_ws + 4;
    int*      DEG    = (int*)(CONV + total);          // N
    int*      ROWPTR = DEG + NNODES;                  // N+1
    int*      CURSOR = ROWPTR + NNODES + 1;           // N
    int2*     CSR    = (int2*)(CURSOR + NNODES + 1);  // E (src, eid), 8B aligned
    float*    POOL   = (float*)(CSR + NEDGES);        // G*64
    float*    CNT    = POOL + NGRAPH * 64;            // G
    float*    XLb    = CNT + NGRAPH;                  // N*256
    float*    XRb    = XLb + NNODES * 256;            // N*256
    float*    ACC    = XRb + NNODES * 256;            // N*256 (layer io)

    const float* CX  = CONV + S.off[0];
    const float* CEA = CONV + S.off[1];
    const float* CP[21];
    for (int i = 0; i < 21; i++) CP[i] = CONV + S.off[2 + i];
    const float* CmW1 = CONV + S.off[23];
    const float* Cmb1 = CONV + S.off[24];
    const float* CmW2 = CONV + S.off[25];
    const float* Cmb2 = CONV + S.off[26];
    const float* CmW3 = CONV + S.off[27];
    const float* Cmb3 = CONV + S.off[28];

    // ---- sniff + canonicalize ----
    sniff_all<<<1, 256, 0, stream>>>(d_in[0], ei, batch, FLAGS);
    convert_inputs<<<(total + 255) / 256, 256, 0, stream>>>(S, FLAGS, CONV, total);

    // ---- CSR build (graph identical across layers: build once) ----
    hipMemsetAsync(DEG, 0, sizeof(int) * NNODES, stream);
    csr_hist<<<(NEDGES + 255) / 256, 256, 0, stream>>>(ei, FLAGS, DEG);
    csr_scan<<<1, 1024, 0, stream>>>(DEG, ROWPTR, CURSOR);
    csr_scatter<<<(NEDGES + 255) / 256, 256, 0, stream>>>(ei, FLAGS, CURSOR, CSR);

    // ---- layer 1: x (N x 12) -> ACC (N x 256), ELU ----
    lin_lr<8, 12><<<(NNODES + 7) / 8, 256, 0, stream>>>(CX, 256, CP[0], CP[1], CP[2], CP[3], XLb, XRb);
    gat_agg<4, true><<<NNODES, 256, 0, stream>>>(ROWPTR, CSR, XLb, XRb, CEA, CP[4], CP[5], CP[6], ACC);

    // ---- layer 2: ACC (N x 256) -> ACC, ELU ----
    lin_lr<16, 256><<<(NNODES + 15) / 16, 256, 0, stream>>>(ACC, 256, CP[7], CP[8], CP[9], CP[10], XLb, XRb);
    gat_agg<4, true><<<NNODES, 256, 0, stream>>>(ROWPTR, CSR, XLb, XRb, CEA, CP[11], CP[12], CP[13], ACC);

    // ---- layer 3: ACC (N x 256) -> ACC (N x 64), no act ----
    lin_lr<8, 256><<<(NNODES + 7) / 8, 64, 0, stream>>>(ACC, 64, CP[14], CP[15], CP[16], CP[17], XLb, XRb);
    gat_agg<1, false><<<NNODES, 64, 0, stream>>>(ROWPTR, CSR, XLb, XRb, CEA, CP[18], CP[19], CP[20], ACC);

    // ---- global mean pool + MLP head ----
    hipMemsetAsync(POOL, 0, sizeof(float) * (NGRAPH * 64 + NGRAPH), stream);
    pool_kernel<<<(NNODES * 64 + 255) / 256, 256, 0, stream>>>(ACC, batch, FLAGS, POOL, CNT);
    mlp_head<<<NGRAPH, 64, 0, stream>>>(POOL, CNT, CmW1, Cmb1, CmW2, Cmb2, CmW3, Cmb3, (float*)d_out);
}

// Round 5
// 575.508 us; speedup vs baseline: 2.8204x; 1.1703x over previous
//
#include <hip/hip_runtime.h>
#include <hip/hip_bf16.h>

#define NNODES 20000
#define NEDGES 320000
#define NGRAPH 1000

typedef __hip_bfloat16 bf16;

__device__ __forceinline__ float b2f(bf16 x) { return __bfloat162float(x); }

// width-agnostic index fetch (int32 or int64 storage)
__device__ __forceinline__ int idx_at(const void* p, int i, int is64) {
    return is64 ? (int)((const long long*)p)[i] : ((const int*)p)[i];
}

// ---------------------------------------------------------------------------
// sniff input encodings (flags[0]: floats bf16?, flags[1]: ei int64?, flags[2]: batch int64?)
// ---------------------------------------------------------------------------
__global__ void sniff_all(const void* __restrict__ x, const void* __restrict__ ei,
                          const void* __restrict__ batch, int* __restrict__ flags) {
    __shared__ int sb[4];
    if (threadIdx.x < 4) sb[threadIdx.x] = 0;
    __syncthreads();
    int gb = 0, gf = 0, ze = 0, zb = 0;
    for (int i = threadIdx.x; i < 8192; i += blockDim.x) {
        float vb = b2f(((const bf16*)x)[i]);
        float vf = ((const float*)x)[i];
        if (fabsf(vb) < 1e4f) gb++;
        if (fabsf(vf) < 1e4f) gf++;
        if (((const int*)ei)[2 * i + 1] == 0) ze++;
        if (((const int*)batch)[2 * i + 1] == 0) zb++;
    }
    atomicAdd(&sb[0], gb); atomicAdd(&sb[1], gf);
    atomicAdd(&sb[2], ze); atomicAdd(&sb[3], zb);
    __syncthreads();
    if (threadIdx.x == 0) {
        flags[0] = (sb[0] >= sb[1]) ? 1 : 0;
        flags[1] = (sb[2] > 6000) ? 1 : 0;
        flags[2] = (sb[3] > 6000) ? 1 : 0;
    }
}

// ---------------------------------------------------------------------------
// canonicalize all float inputs into fp32 scratch
// ---------------------------------------------------------------------------
struct Segs {
    const void* src[29];
    int off[30];
};

__global__ void convert_inputs(Segs S, const int* __restrict__ flags,
                               float* __restrict__ dst, int total) {
    int i = blockIdx.x * blockDim.x + threadIdx.x;
    if (i >= total) return;
    bool isbf = flags[0] != 0;
    int s = 0;
    while (i >= S.off[s + 1]) s++;
    int j = i - S.off[s];
    dst[i] = isbf ? b2f(((const bf16*)S.src[s])[j]) : ((const float*)S.src[s])[j];
}

// ---------------------------------------------------------------------------
// CSR build: histogram -> single-block scan -> scatter (dst-sorted edge list)
// ---------------------------------------------------------------------------
__global__ void csr_hist(const void* __restrict__ ei, const int* __restrict__ flags,
                         int* __restrict__ deg) {
    int e = blockIdx.x * blockDim.x + threadIdx.x;
    if (e >= NEDGES) return;
    atomicAdd(&deg[idx_at(ei, NEDGES + e, flags[1])], 1);
}

__global__ void csr_scan(const int* __restrict__ deg, int* __restrict__ rowptr,
                         int* __restrict__ cursor) {
    __shared__ int buf[1024];
    __shared__ int carry;
    int t = threadIdx.x;
    if (t == 0) carry = 0;
    __syncthreads();
    for (int base = 0; base < NNODES; base += 1024) {
        int i = base + t;
        int v = (i < NNODES) ? deg[i] : 0;
        buf[t] = v;
        __syncthreads();
        for (int o = 1; o < 1024; o <<= 1) {
            int add = (t >= o) ? buf[t - o] : 0;
            __syncthreads();
            buf[t] += add;
            __syncthreads();
        }
        int incl = buf[t];
        int excl = incl - v;
        int c0 = carry;  // stable: last write was before a barrier
        if (i < NNODES) { rowptr[i] = c0 + excl; cursor[i] = c0 + excl; }
        __syncthreads();
        if (t == 1023) carry = c0 + incl;
        __syncthreads();
    }
    if (t == 0) rowptr[NNODES] = carry;
}

__global__ void csr_scatter(const void* __restrict__ ei, const int* __restrict__ flags,
                            int* __restrict__ cursor, int2* __restrict__ csr) {
    int e = blockIdx.x * blockDim.x + threadIdx.x;
    if (e >= NEDGES) return;
    const int i64 = flags[1];
    int src = idx_at(ei, e, i64), dst = idx_at(ei, NEDGES + e, i64);
    int pos = atomicAdd(&cursor[dst], 1);
    csr[pos] = make_int2(src, e);
}

// ---------------------------------------------------------------------------
// Fused lin_l / lin_r: XL = X@Wl + bl, XR = X@Wr + br
// block = Dout threads, R rows per block, X rows staged transposed in LDS
// ---------------------------------------------------------------------------
template <int R, int CIN>
__global__ void lin_lr(const float* __restrict__ X, int Dout,
                       const float* __restrict__ Wl, const float* __restrict__ bl,
                       const float* __restrict__ Wr, const float* __restrict__ br,
                       float* __restrict__ XL, float* __restrict__ XR) {
    __shared__ float xs[CIN * R];
    const int c = threadIdx.x;
    const int r0 = blockIdx.x * R;

    for (int i = c; i < R * CIN; i += blockDim.x) {
        int r = i / CIN, k = i - r * CIN;
        int row = r0 + r;
        xs[k * R + r] = (row < NNODES) ? X[row * CIN + k] : 0.f;
    }
    __syncthreads();

    float accL[R], accR[R];
#pragma unroll
    for (int r = 0; r < R; r++) { accL[r] = 0.f; accR[r] = 0.f; }

    for (int k = 0; k < CIN; k++) {
        float wl = Wl[k * Dout + c];
        float wr = Wr[k * Dout + c];
#pragma unroll
        for (int r = 0; r < R; r++) {
            float xv = xs[k * R + r];
            accL[r] = fmaf(xv, wl, accL[r]);
            accR[r] = fmaf(xv, wr, accR[r]);
        }
    }
    float bL = bl[c], bR = br[c];
#pragma unroll
    for (int r = 0; r < R; r++) {
        int row = r0 + r;
        if (row < NNODES) {
            XL[row * Dout + c] = accL[r] + bL;
            XR[row * Dout + c] = accR[r] + bR;
        }
    }
}

// ---------------------------------------------------------------------------
// branchless online-softmax update; v is wave-uniform
// first edge: m=-inf -> nm=v, p=1, sc=exp(-inf)=0 -> l=1, acc=xl
// ---------------------------------------------------------------------------
__device__ __forceinline__ void osm_update(float& m, float& l, float& acc,
                                           float v, float xl) {
    float nm = fmaxf(m, v);
    float p = __expf(v - nm);
    float sc = __expf(m - nm);
    l = fmaf(l, sc, p);
    acc = fmaf(acc, sc, p * xl);
    m = nm;
}

// ---------------------------------------------------------------------------
// Fused GATv2 edge pipeline, one block per dst node, one wave per head.
// Online softmax over the dst's CSR list; edges processed in chunks of 4 so
// 4 XL-row gathers are in flight and the 4 shuffle butterflies interleave.
// ---------------------------------------------------------------------------
template <int H, bool ELU>
__global__ void gat_agg(const int* __restrict__ rowptr, const int2* __restrict__ csr,
                        const float* __restrict__ XL, const float* __restrict__ XR,
                        const float* __restrict__ ea,   // [E][4] fp32, 16B aligned
                        const float* __restrict__ We, const float* __restrict__ att,
                        const float* __restrict__ bias, float* __restrict__ out) {
    const int Dout = H * 64;
    const int dst = blockIdx.x;
    const int t = threadIdx.x;  // channel c = h*64 + lane; wave == head

    float xr = XR[dst * Dout + t];
    float w0 = We[0 * Dout + t], w1 = We[1 * Dout + t];
    float w2 = We[2 * Dout + t], w3 = We[3 * Dout + t];
    float av = att[t];

    int i0 = rowptr[dst], i1 = rowptr[dst + 1];
    float m = -INFINITY, l = 0.f, acc = 0.f;

    int i = i0;
    for (; i + 4 <= i1; i += 4) {
        int2 se0 = csr[i], se1 = csr[i + 1], se2 = csr[i + 2], se3 = csr[i + 3];
        float xl0 = XL[se0.x * Dout + t];
        float xl1 = XL[se1.x * Dout + t];
        float xl2 = XL[se2.x * Dout + t];
        float xl3 = XL[se3.x * Dout + t];
        float4 a0 = ((const float4*)ea)[se0.y];
        float4 a1 = ((const float4*)ea)[se1.y];
        float4 a2 = ((const float4*)ea)[se2.y];
        float4 a3 = ((const float4*)ea)[se3.y];

        float z0 = fmaf(a0.x, w0, fmaf(a0.y, w1, fmaf(a0.z, w2, fmaf(a0.w, w3, xl0 + xr))));
        float z1 = fmaf(a1.x, w0, fmaf(a1.y, w1, fmaf(a1.z, w2, fmaf(a1.w, w3, xl1 + xr))));
        float z2 = fmaf(a2.x, w0, fmaf(a2.y, w1, fmaf(a2.z, w2, fmaf(a2.w, w3, xl2 + xr))));
        float z3 = fmaf(a3.x, w0, fmaf(a3.y, w1, fmaf(a3.z, w2, fmaf(a3.w, w3, xl3 + xr))));
        float v0 = (z0 > 0.f ? z0 : 0.2f * z0) * av;
        float v1 = (z1 > 0.f ? z1 : 0.2f * z1) * av;
        float v2 = (z2 > 0.f ? z2 : 0.2f * z2) * av;
        float v3 = (z3 > 0.f ? z3 : 0.2f * z3) * av;
#pragma unroll
        for (int o = 32; o; o >>= 1) {
            v0 += __shfl_xor(v0, o);
            v1 += __shfl_xor(v1, o);
            v2 += __shfl_xor(v2, o);
            v3 += __shfl_xor(v3, o);
        }
        osm_update(m, l, acc, v0, xl0);
        osm_update(m, l, acc, v1, xl1);
        osm_update(m, l, acc, v2, xl2);
        osm_update(m, l, acc, v3, xl3);
    }
    for (; i < i1; i++) {
        int2 se = csr[i];
        float4 e4 = ((const float4*)ea)[se.y];
        float xl = XL[se.x * Dout + t];
        float z = fmaf(e4.x, w0, fmaf(e4.y, w1, fmaf(e4.z, w2, fmaf(e4.w, w3, xl + xr))));
        float v = (z > 0.f ? z : 0.2f * z) * av;
#pragma unroll
        for (int o = 32; o; o >>= 1) v += __shfl_xor(v, o);
        osm_update(m, l, acc, v, xl);
    }

    float o = acc / (l + 1e-16f) + bias[t];
    if (ELU) o = o > 0.f ? o : expf(o) - 1.f;
    out[dst * Dout + t] = o;
}

// ---------------------------------------------------------------------------
// mean pool (atomic) over batch
// ---------------------------------------------------------------------------
__global__ void pool_kernel(const float* __restrict__ h, const void* __restrict__ batch,
                            const int* __restrict__ flags,
                            float* __restrict__ pool, float* __restrict__ cnt) {
    int i = blockIdx.x * blockDim.x + threadIdx.x;
    if (i >= NNODES * 64) return;
    int n = i >> 6, c = i & 63;
    int b = idx_at(batch, n, flags[2]);
    atomicAdd(&pool[b * 64 + c], h[i]);
    if (c == 0) atomicAdd(&cnt[b], 1.f);
}

// ---------------------------------------------------------------------------
// MLP head: one block (64 threads) per graph; fp32 output
// ---------------------------------------------------------------------------
__global__ void mlp_head(const float* __restrict__ pool, const float* __restrict__ cnt,
                         const float* __restrict__ mW1, const float* __restrict__ mb1,
                         const float* __restrict__ mW2, const float* __restrict__ mb2,
                         const float* __restrict__ mW3, const float* __restrict__ mb3,
                         float* __restrict__ out) {
    __shared__ float g[64], s1[32], s2[16];
    int b = blockIdx.x, t = threadIdx.x;
    float c = fmaxf(cnt[b], 1.f);
    g[t] = pool[b * 64 + t] / c;
    __syncthreads();
    if (t < 32) {
        float a = 0.f;
        for (int k = 0; k < 64; k++) a = fmaf(g[k], mW1[k * 32 + t], a);
        s1[t] = fmaxf(a + mb1[t], 0.f);
    }
    __syncthreads();
    if (t < 16) {
        float a = 0.f;
        for (int k = 0; k < 32; k++) a = fmaf(s1[k], mW2[k * 16 + t], a);
        s2[t] = fmaxf(a + mb2[t], 0.f);
    }
    __syncthreads();
    if (t < 4) {
        float a = 0.f;
        for (int k = 0; k < 16; k++) a = fmaf(s2[k], mW3[k * 4 + t], a);
        out[b * 4 + t] = a + mb3[t];
    }
}

// ---------------------------------------------------------------------------

extern "C" void kernel_launch(void* const* d_in, const int* in_sizes, int n_in,
                              void* d_out, int out_size, void* d_ws, size_t ws_size,
                              hipStream_t stream) {
    const void* ei    = d_in[1];
    const void* batch = d_in[3];

    // ---- canonicalization table: the 29 float inputs in dict order ----
    int fidx[29];
    fidx[0] = 0;  // x
    fidx[1] = 2;  // edge_attr
    for (int i = 0; i < 21; i++) fidx[2 + i] = 4 + i;
    for (int i = 0; i < 6; i++) fidx[23 + i] = 25 + i;

    Segs S;
    int off = 0;
    for (int i = 0; i < 29; i++) {
        S.src[i] = d_in[fidx[i]];
        S.off[i] = off;
        off += in_sizes[fidx[i]];
    }
    S.off[29] = off;
    const int total = off;

    // ---- workspace layout ----
    int*      FLAGS  = (int*)d_ws;                    // 4 ints (16 B, keeps alignment)
    float*    CONV   = (float*)d_ws + 4;
    int*      DEG    = (int*)(CONV + total);          // N
    int*      ROWPTR = DEG + NNODES;                  // N+1
    int*      CURSOR = ROWPTR + NNODES + 1;           // N
    int2*     CSR    = (int2*)(CURSOR + NNODES + 1);  // E (src, eid), 8B aligned
    float*    POOL   = (float*)(CSR + NEDGES);        // G*64
    float*    CNT    = POOL + NGRAPH * 64;            // G
    float*    XLb    = CNT + NGRAPH;                  // N*256
    float*    XRb    = XLb + NNODES * 256;            // N*256
    float*    ACC    = XRb + NNODES * 256;            // N*256 (layer io)

    const float* CX  = CONV + S.off[0];
    const float* CEA = CONV + S.off[1];
    const float* CP[21];
    for (int i = 0; i < 21; i++) CP[i] = CONV + S.off[2 + i];
    const float* CmW1 = CONV + S.off[23];
    const float* Cmb1 = CONV + S.off[24];
    const float* CmW2 = CONV + S.off[25];
    const float* Cmb2 = CONV + S.off[26];
    const float* CmW3 = CONV + S.off[27];
    const float* Cmb3 = CONV + S.off[28];

    // ---- sniff + canonicalize ----
    sniff_all<<<1, 256, 0, stream>>>(d_in[0], ei, batch, FLAGS);
    convert_inputs<<<(total + 255) / 256, 256, 0, stream>>>(S, FLAGS, CONV, total);

    // ---- CSR build (graph identical across layers: build once) ----
    hipMemsetAsync(DEG, 0, sizeof(int) * NNODES, stream);
    csr_hist<<<(NEDGES + 255) / 256, 256, 0, stream>>>(ei, FLAGS, DEG);
    csr_scan<<<1, 1024, 0, stream>>>(DEG, ROWPTR, CURSOR);
    csr_scatter<<<(NEDGES + 255) / 256, 256, 0, stream>>>(ei, FLAGS, CURSOR, CSR);

    // ---- layer 1: x (N x 12) -> ACC (N x 256), ELU ----
    lin_lr<8, 12><<<(NNODES + 7) / 8, 256, 0, stream>>>(CX, 256, CP[0], CP[1], CP[2], CP[3], XLb, XRb);
    gat_agg<4, true><<<NNODES, 256, 0, stream>>>(ROWPTR, CSR, XLb, XRb, CEA, CP[4], CP[5], CP[6], ACC);

    // ---- layer 2: ACC (N x 256) -> ACC, ELU ----
    lin_lr<16, 256><<<(NNODES + 15) / 16, 256, 0, stream>>>(ACC, 256, CP[7], CP[8], CP[9], CP[10], XLb, XRb);
    gat_agg<4, true><<<NNODES, 256, 0, stream>>>(ROWPTR, CSR, XLb, XRb, CEA, CP[11], CP[12], CP[13], ACC);

    // ---- layer 3: ACC (N x 256) -> ACC (N x 64), no act ----
    lin_lr<8, 256><<<(NNODES + 7) / 8, 64, 0, stream>>>(ACC, 64, CP[14], CP[15], CP[16], CP[17], XLb, XRb);
    gat_agg<1, false><<<NNODES, 64, 0, stream>>>(ROWPTR, CSR, XLb, XRb, CEA, CP[18], CP[19], CP[20], ACC);

    // ---- global mean pool + MLP head ----
    hipMemsetAsync(POOL, 0, sizeof(float) * (NGRAPH * 64 + NGRAPH), stream);
    pool_kernel<<<(NNODES * 64 + 255) / 256, 256, 0, stream>>>(ACC, batch, FLAGS, POOL, CNT);
    mlp_head<<<NGRAPH, 64, 0, stream>>>(POOL, CNT, CmW1, Cmb1, CmW2, Cmb2, CmW3, Cmb3, (float*)d_out);
}